// Round 5
// baseline (268.099 us; speedup 1.0000x reference)
//
#include <hip/hip_runtime.h>
#include <hip/hip_bf16.h>

#define NN 50000
#define NE 800000
#define FD 256
#define NN_PAD 50048       // NN rounded up to multiple of 64
#define SCAN_B 196         // ceil(NN/256)
#define NPB 16             // nodes per block

typedef __attribute__((ext_vector_type(8))) short bf16x8;
typedef __attribute__((ext_vector_type(16))) short short16;
typedef __attribute__((ext_vector_type(4))) float f32x4;
typedef unsigned long long ull;

__device__ __forceinline__ short f2bf(float f) {
    union { float f; unsigned u; } v; v.f = f;
    unsigned r = v.u + 0x7fffu + ((v.u >> 16) & 1u);
    return (short)(r >> 16);
}
__device__ __forceinline__ float bf2f(unsigned short u) {
    union { unsigned u; float f; } v; v.u = ((unsigned)u) << 16;
    return v.f;
}

// dc[row] += (1<<40) | fix24(cv)   -- one 64b atomic per edge
__global__ void count_deg_kernel(const int* __restrict__ row, const float* __restrict__ cv,
                                 ull* __restrict__ dc) {
    int e = blockIdx.x * blockDim.x + threadIdx.x;
    if (e < NE) {
        int r = row[e];
        unsigned cf = (unsigned)(cv[e] * 16777216.0f + 0.5f);
        atomicAdd(&dc[r], (1ULL << 40) | (ull)cf);
    }
}

__device__ __forceinline__ int block_excl_scan256(int v, int tid) {
    __shared__ int ws[4];
    int lane = tid & 63, wv = tid >> 6;
    int incl = v;
#pragma unroll
    for (int off = 1; off < 64; off <<= 1) {
        int t = __shfl_up(incl, off);
        if (lane >= off) incl += t;
    }
    if (lane == 63) ws[wv] = incl;
    __syncthreads();
    int acc = 0;
#pragma unroll
    for (int k = 0; k < 4; ++k) if (k < wv) acc += ws[k];
    return acc + incl - v;
}

// per-block count sums -> bsum; dinv = deg^-1/2 (0 if deg==0)
__global__ void sum_dinv_kernel(const ull* __restrict__ dc, float* __restrict__ dinv,
                                int* __restrict__ bsum) {
    int i = blockIdx.x * 256 + threadIdx.x;
    ull v = (i < NN) ? dc[i] : 0ULL;
    int cnt = (int)(v >> 40);
    ull df = v & ((1ULL << 40) - 1);
    int lane = threadIdx.x & 63, wv = threadIdx.x >> 6;
    int s = cnt;
#pragma unroll
    for (int off = 1; off < 64; off <<= 1) s += __shfl_xor(s, off);
    __shared__ int ws[4];
    if (lane == 0) ws[wv] = s;
    __syncthreads();
    if (threadIdx.x == 0) bsum[blockIdx.x] = ws[0] + ws[1] + ws[2] + ws[3];
    if (i < NN) {
        float d = (float)df * (1.0f / 16777216.0f);
        dinv[i] = (df > 0) ? rsqrtf(d) : 0.f;
    }
}

__global__ void scan_bsum_kernel(int* __restrict__ bsum) {
    int tid = threadIdx.x;
    int v = (tid < SCAN_B) ? bsum[tid] : 0;
    int excl = block_excl_scan256(v, tid);
    if (tid < SCAN_B) bsum[tid] = excl;
}

__global__ void write_rs_kernel(const ull* __restrict__ dc, const int* __restrict__ bsum,
                                int* __restrict__ rs, int* __restrict__ cursor) {
    int i = blockIdx.x * 256 + threadIdx.x;
    int v = (i < NN) ? (int)(dc[i] >> 40) : 0;
    int excl = block_excl_scan256(v, threadIdx.x) + bsum[blockIdx.x];
    if (i < NN) { rs[i] = excl; cursor[i] = excl; }
    if (i == NN - 1) rs[NN] = excl + v;
}

// xbs = bf16(x * dinv[row]); Wb = bf16(W)
__global__ void convert_kernel(const float* __restrict__ x, const float* __restrict__ W,
                               const float* __restrict__ dinv,
                               short* __restrict__ xbs, short* __restrict__ Wb) {
    size_t i = ((size_t)blockIdx.x * blockDim.x + threadIdx.x) * 4;
    const size_t NX = (size_t)NN * FD;
    if (i < NX) {
        float dr = dinv[i >> 8];
        float4 v = *(const float4*)(x + i);
        short* d = xbs + i;
        d[0] = f2bf(v.x * dr); d[1] = f2bf(v.y * dr);
        d[2] = f2bf(v.z * dr); d[3] = f2bf(v.w * dr);
    } else {
        size_t j = i - NX;
        if (j < (size_t)FD * FD) {
            float4 v = *(const float4*)(W + j);
            short* d = Wb + j;
            d[0] = f2bf(v.x); d[1] = f2bf(v.y); d[2] = f2bf(v.z); d[3] = f2bf(v.w);
        }
    }
}

// counting-sort edges by destination; pack (cv_fix16:16 | col:16) into 4 bytes
__global__ void bucket_kernel(const int* __restrict__ row, const int* __restrict__ col,
                              const float* __restrict__ cv,
                              int* __restrict__ cursor, unsigned* __restrict__ e_cw) {
    int e = blockIdx.x * blockDim.x + threadIdx.x;
    if (e >= NE) return;
    int r = row[e], c = col[e];
    int idx = atomicAdd(&cursor[r], 1);
    unsigned cf = (unsigned)fminf(cv[e] * 65536.0f + 0.5f, 65535.0f);
    e_cw[idx] = (cf << 16) | (unsigned)c;
}

// fused gather + GEMM. Block = 16 nodes, 256 threads, 16 quads.
// Quads split the block's CSR edge range into equal contiguous chunks,
// accumulate in registers (unroll-4: 4 x-row loads in flight per quad),
// flush to LDS f32 accumulators (ds atomics) at node boundaries.
__global__ __launch_bounds__(256) void fused_kernel(
        const short* __restrict__ xbs, const unsigned* __restrict__ e_cw,
        const int* __restrict__ rs, const float* __restrict__ dinv,
        const short* __restrict__ Wb, const float* __restrict__ bias,
        float* __restrict__ out) {
    __shared__ float Af[NPB][264];
    __shared__ short Ab[NPB][264];
    __shared__ int rsl[NPB + 1];
    int tid = threadIdx.x, lane = tid & 63, wv = tid >> 6;
    int nbase = blockIdx.x * NPB;
    int qg = tid >> 4;      // quad 0..15
    int i  = tid & 15;      // lane within quad

    for (int t = tid; t < NPB * 264; t += 256) ((float*)Af)[t] = 0.f;
    if (tid <= NPB) rsl[tid] = rs[nbase + tid];
    __syncthreads();

    int eb = rsl[0], ee = rsl[NPB];
    int ne = ee - eb;
    int C  = (ne + NPB - 1) >> 4;
    int e    = eb + qg * C;
    int eend = min(e + C, ee);

    if (e < eend) {
        int nidx = 0;
        while (rsl[nidx + 1] <= e) ++nidx;
        int nb = rsl[nidx + 1];
        const short* xq = xbs + i * 16;

        float acc[16];
#pragma unroll
        for (int k = 0; k < 16; ++k) acc[k] = 0.f;

        auto flush_adv = [&]() {
#pragma unroll
            for (int k = 0; k < 16; ++k) {
                atomicAdd(&Af[nidx][i * 16 + k], acc[k]);
                acc[k] = 0.f;
            }
            ++nidx; nb = rsl[nidx + 1];
        };
        auto accum = [&](short16 v, float cvf) {
#pragma unroll
            for (int k = 0; k < 16; ++k)
                acc[k] = fmaf(cvf, bf2f((unsigned short)v[k]), acc[k]);
        };

        // head-peel to 16B alignment of e_cw + e
        while (e < eend && (e & 3)) {
            unsigned cw = e_cw[e];
            short16 v = *(const short16*)(xq + (size_t)(cw & 0xFFFFu) * FD);
            while (e >= nb) flush_adv();
            accum(v, (float)(cw >> 16));
            ++e;
        }
        // main: 4 edges per iteration, 4 x-row loads in flight
        for (; e + 4 <= eend; e += 4) {
            uint4 cw4 = *(const uint4*)(e_cw + e);
            short16 v0 = *(const short16*)(xq + (size_t)(cw4.x & 0xFFFFu) * FD);
            short16 v1 = *(const short16*)(xq + (size_t)(cw4.y & 0xFFFFu) * FD);
            short16 v2 = *(const short16*)(xq + (size_t)(cw4.z & 0xFFFFu) * FD);
            short16 v3 = *(const short16*)(xq + (size_t)(cw4.w & 0xFFFFu) * FD);
            while (e     >= nb) flush_adv();
            accum(v0, (float)(cw4.x >> 16));
            while (e + 1 >= nb) flush_adv();
            accum(v1, (float)(cw4.y >> 16));
            while (e + 2 >= nb) flush_adv();
            accum(v2, (float)(cw4.z >> 16));
            while (e + 3 >= nb) flush_adv();
            accum(v3, (float)(cw4.w >> 16));
        }
        // tail
        for (; e < eend; ++e) {
            unsigned cw = e_cw[e];
            short16 v = *(const short16*)(xq + (size_t)(cw & 0xFFFFu) * FD);
            while (e >= nb) flush_adv();
            accum(v, (float)(cw >> 16));
        }
        // final flush (no advance)
#pragma unroll
        for (int k = 0; k < 16; ++k) atomicAdd(&Af[nidx][i * 16 + k], acc[k]);
    }
    __syncthreads();

    // ---- convert Af (f32) -> Ab (bf16), applying dinv[row] / 65536
    {
        float s = dinv[nbase + qg] * (1.0f / 65536.0f);
        bf16x8 lo, hi;
#pragma unroll
        for (int k = 0; k < 8; ++k) {
            lo[k] = f2bf(Af[qg][i * 16 + k] * s);
            hi[k] = f2bf(Af[qg][i * 16 + 8 + k] * s);
        }
        *(bf16x8*)&Ab[qg][i * 16] = lo;
        *(bf16x8*)&Ab[qg][i * 16 + 8] = hi;
    }
    __syncthreads();

    // ---- GEMM: out[nbase..+16][wv*64..+64] via 16x16x32 bf16 MFMA
    int m = lane & 15, g = lane >> 4;
    f32x4 acc0 = {0,0,0,0}, acc1 = {0,0,0,0}, acc2 = {0,0,0,0}, acc3 = {0,0,0,0};
    const short* w0 = Wb + (size_t)(wv * 64 + 0  + m) * FD;
    const short* w1 = Wb + (size_t)(wv * 64 + 16 + m) * FD;
    const short* w2 = Wb + (size_t)(wv * 64 + 32 + m) * FD;
    const short* w3 = Wb + (size_t)(wv * 64 + 48 + m) * FD;
#pragma unroll
    for (int ks = 0; ks < 8; ++ks) {
        int ko = ks * 32 + g * 8;
        bf16x8 af = *(const bf16x8*)&Ab[m][ko];
        bf16x8 b0 = *(const bf16x8*)(w0 + ko);
        bf16x8 b1 = *(const bf16x8*)(w1 + ko);
        bf16x8 b2 = *(const bf16x8*)(w2 + ko);
        bf16x8 b3 = *(const bf16x8*)(w3 + ko);
        acc0 = __builtin_amdgcn_mfma_f32_16x16x32_bf16(af, b0, acc0, 0, 0, 0);
        acc1 = __builtin_amdgcn_mfma_f32_16x16x32_bf16(af, b1, acc1, 0, 0, 0);
        acc2 = __builtin_amdgcn_mfma_f32_16x16x32_bf16(af, b2, acc2, 0, 0, 0);
        acc3 = __builtin_amdgcn_mfma_f32_16x16x32_bf16(af, b3, acc3, 0, 0, 0);
    }
#pragma unroll
    for (int nt = 0; nt < 4; ++nt) {
        f32x4 a = nt == 0 ? acc0 : nt == 1 ? acc1 : nt == 2 ? acc2 : acc3;
        int c = wv * 64 + nt * 16 + m;
        float bv = bias[c];
#pragma unroll
        for (int r = 0; r < 4; ++r) {
            out[(size_t)(nbase + g * 4 + r) * FD + c] = a[r] + bv;
        }
    }
}

extern "C" void kernel_launch(void* const* d_in, const int* in_sizes, int n_in,
                              void* d_out, int out_size, void* d_ws, size_t ws_size,
                              hipStream_t stream) {
    const float* x  = (const float*)d_in[0];
    const int*   ei = (const int*)d_in[1];
    const float* cv = (const float*)d_in[2];
    const float* W  = (const float*)d_in[3];
    const float* b  = (const float*)d_in[4];
    float* out = (float*)d_out;

    const int* row = ei;
    const int* col = ei + NE;

    // ws layout
    ull*      dc     = (ull*)d_ws;                         // NN_PAD * 8B
    unsigned* e_cw   = (unsigned*)(dc + NN_PAD);           // NE * 4B
    short*    xbs    = (short*)(e_cw + NE);                // NN*FD * 2B
    short*    Wb     = xbs + (size_t)NN * FD;              // FD*FD * 2B
    float*    dinv   = (float*)(Wb + (size_t)FD * FD);     // NN_PAD
    int*      rs     = (int*)(dinv + NN_PAD);              // NN_PAD (uses NN+1)
    int*      cursor = rs + NN_PAD;                        // NN_PAD
    int*      bsum   = cursor + NN_PAD;                    // 256

    hipMemsetAsync(dc, 0, NN_PAD * sizeof(ull), stream);

    count_deg_kernel<<<(NE + 255) / 256, 256, 0, stream>>>(row, cv, dc);
    sum_dinv_kernel<<<SCAN_B, 256, 0, stream>>>(dc, dinv, bsum);
    scan_bsum_kernel<<<1, 256, 0, stream>>>(bsum);
    write_rs_kernel<<<SCAN_B, 256, 0, stream>>>(dc, bsum, rs, cursor);
    const size_t NCONV = ((size_t)NN * FD + (size_t)FD * FD) / 4;
    convert_kernel<<<(NCONV + 255) / 256, 256, 0, stream>>>(x, W, dinv, xbs, Wb);
    bucket_kernel<<<(NE + 255) / 256, 256, 0, stream>>>(row, col, cv, cursor, e_cw);

    fused_kernel<<<NN / NPB, 256, 0, stream>>>(xbs, e_cw, rs, dinv, Wb, b, out);
}